// Round 11
// baseline (19.549 us; speedup 1.0000x reference)
//
#include <hip/hip_runtime.h>
#include <hip/hip_bf16.h>

// Fused main kernel + tiny finalize kernel. (R10-validated structure)
//   Y[512 x B] = W[512 x 128] * X[128 x B]
//   W rows per m (8): [h_re, h_im, q0_re, q0_im, q1_re, q1_im, q2_re, q2_im]
//   X[:,b] = [amp*cos(ph) (64) ; amp*sin(ph) (64)]
//   pred[b,m] = Y[8m]^2 + Y[8m+1]^2 - sum(Y[8m+2..8m+7]^2); loss = mean((pred-true)^2)
// R11 delta: store only the 4 EVEN (re) rows per m in LDS (64 KB instead of 128);
// odd-row fragments derived in-register: wf_odd[kk] = {-st[2],-st[3],st[0],st[1]}
// (bf16 negate = sign-XOR, exact). LDS 72 KB -> 2 blocks/CU: 512 blocks x 256 thr,
// cross-block overlap of prologue/W-build with the partner block's MFMA loop.
// Trig: Taylor sincos (validated R8/R10). Cross-block handoff: kernel boundary
// (validated R10; all non-fence in-kernel tails race on gfx950: R6/R7/R9).

typedef short s16x8 __attribute__((ext_vector_type(8)));
typedef float f32x4 __attribute__((ext_vector_type(4)));
typedef unsigned int u32x4 __attribute__((ext_vector_type(4)));

#define B_TOTAL 32768

constexpr double PI_ = 3.14159265358979323846;
constexpr double RHO_ = 1.225, CS_ = 343.0, FREQ_ = 40000.0, UU_ = 3.086, AREA_ = 0.0008;
constexpr double KW_ = 2.0 * PI_ * FREQ_ / CS_;
constexpr double WW_ = 2.0 * PI_ * FREQ_;
constexpr double RR_ = 0.000865;
constexpr double CONSTV_ = 2.0 * PI_ * RR_ * RR_ * RR_;
constexpr double C1E5_ = CONSTV_ / (6.0 * RHO_ * CS_ * CS_) * 100000.0;
constexpr double C2E5_ = CONSTV_ * RHO_ / 4.0 * 100000.0;   // = -C2 * 1e5
constexpr double GG_ = AREA_ * RHO_ * CS_ * KW_ * UU_ / (2.0 * PI_);

__device__ inline unsigned int pk2(float a, float b) {   // -> v_cvt_pk_bf16_f32
    __hip_bfloat162 h = __float22bfloat162_rn(make_float2(a, b));
    unsigned int u;
    __builtin_memcpy(&u, &h, 4);
    return u;
}

__device__ inline s16x8 negbf(s16x8 x) {   // exact bf16 negation (sign-bit XOR)
    u32x4 u;
    __builtin_memcpy(&u, &x, 16);
    u ^= (u32x4){0x80008000u, 0x80008000u, 0x80008000u, 0x80008000u};
    s16x8 r;
    __builtin_memcpy(&r, &u, 16);
    return r;
}

// Branchless Taylor sincos for u in [-pi, pi]. |err| <= ~1e-6. (validated R8)
__device__ inline void poly_sincos(float u, float& s, float& c) {
    float u2 = u * u;
    float sp = fmaf(u2, -7.6471637e-13f, 1.6059044e-10f);
    sp = fmaf(u2, sp, -2.5052108e-8f);
    sp = fmaf(u2, sp, 2.7557319e-6f);
    sp = fmaf(u2, sp, -1.9841270e-4f);
    sp = fmaf(u2, sp, 8.3333335e-3f);
    sp = fmaf(u2, sp, -0.16666667f);
    s = u * fmaf(u2, sp, 1.0f);
    float cp = fmaf(u2, -1.1470746e-11f, 2.0876757e-9f);
    cp = fmaf(u2, cp, -2.7557319e-7f);
    cp = fmaf(u2, cp, 2.4801587e-5f);
    cp = fmaf(u2, cp, -1.3888889e-3f);
    cp = fmaf(u2, cp, 4.1666668e-2f);
    cp = fmaf(u2, cp, -0.5f);
    c = fmaf(u2, cp, 1.0f);
}

// sin/cos(2*pi*t) for t ~ O(16): reduce to [-0.5,0.5], scale.
__device__ inline void sincos_2pit(float t, float& s, float& c) {
    float x = t - rintf(t);
    poly_sincos(x * 6.2831853e+0f, s, c);
}

// sin/cos(p) for p in [0, 2*pi): one Cody-Waite step.
__device__ inline void sincos_rad(float p, float& s, float& c) {
    const float INV2PI = 0.15915494309189535f;
    float n = rintf(p * INV2PI);
    poly_sincos(fmaf(n, -6.2831853e+0f, p), s, c);
}

__global__ __launch_bounds__(256, 2)
void fused_energy(const float* __restrict__ amp, const float* __restrict__ ph,
                  const float* __restrict__ te,
                  double* __restrict__ partials) {
    __shared__ unsigned short Wl[256 * 128];     // 64 KB: 4 re-rows per m, swizzled
    __shared__ unsigned short Xt[2][16 * 128];   // 2 x 4 KB double buffer
    __shared__ double sred[4];

    const int t = threadIdx.x;
    const int wave = t >> 6, lane = t & 63;      // wave 0..3 = Y-row quartet
    const int lrow = lane & 15, lkgrp = lane >> 4;
    const int blk = blockIdx.x;
    const int xc = t >> 4, xn4 = t & 15;         // X-build: col 0..15, n-quad 0..15

    // ---- prologue loads: tiles 0,1 amp/ph (float4) + tile0 te ----
    const int baseA = (blk * 64 + xc) * 64 + xn4 * 4;
    float4 am0 = *reinterpret_cast<const float4*>(amp + baseA);
    float4 pv0 = *reinterpret_cast<const float4*>(ph + baseA);
    float4 amCur = *reinterpret_cast<const float4*>(amp + baseA + 16 * 64);
    float4 pvCur = *reinterpret_cast<const float4*>(ph + baseA + 16 * 64);
    const int teB = (blk * 64 + lrow) * 64 + wave * 16 + (lkgrp >> 1);
    float teU[8], teN[8];
#pragma unroll
    for (int rt = 0; rt < 8; ++rt) teU[rt] = te[teB + rt * 2];

    // ---- W build: thread t -> m = t>>2, n in [ (t&3)*16, +16 ); 4 re-rows/m ----
    {
        const float G1 = sqrtf((float)C1E5_) * (float)GG_;
        const float G2 = sqrtf((float)C2E5_) * (float)(GG_ / (WW_ * RHO_));
        const float KWf = (float)KW_;
        const float REVf = (float)(FREQ_ / CS_);
        int mm = t >> 2, nq = t & 3;
        int mx = mm >> 3, my = mm & 7;
        const float dz = 0.10f;
        u32x4 pkp[4][2][2];   // [c2][half][jgroup]
#pragma unroll
        for (int jp = 0; jp < 8; ++jp) {
            float va[8], vb[8];
#pragma unroll
            for (int jj = 0; jj < 2; ++jj) {
                int j = jp * 2 + jj;
                int sx = nq * 2 + (j >> 3), sy = j & 7;
                float dx = ((float)mx - 3.5f) * 0.005f - ((float)sx - 3.5f) * 0.01f;
                float dy = ((float)my - 3.5f) * 0.005f - ((float)sy - 3.5f) * 0.01f;
                float r2 = dx * dx + dy * dy + dz * dz;
                float r = sqrtf(r2);
                float invr = 1.0f / r;
                float kr = KWf * r;
                float S, C;
                sincos_2pit(REVf * r, S, C);       // S=sin(kr), C=cos(kr)
                float hb = G1 * invr;
                float qb = G2 * invr * invr * invr;
                float t1 = kr * S + C, t2 = kr * C - S;
                float* v = jj ? vb : va;
                v[0] = hb * S;       v[1] = hb * C;
                v[2] = qb * dx * t1; v[3] = qb * dx * t2;
                v[4] = qb * dy * t1; v[5] = qb * dy * t2;
                v[6] = qb * dz * t1; v[7] = qb * dz * t2;
            }
#pragma unroll
            for (int c2 = 0; c2 < 4; ++c2) {
                pkp[c2][0][jp >> 2][jp & 3] = pk2(va[2 * c2], vb[2 * c2]);
                pkp[c2][1][jp >> 2][jp & 3] = pk2(-va[2 * c2 + 1], -vb[2 * c2 + 1]);
            }
        }
#pragma unroll
        for (int c2 = 0; c2 < 4; ++c2) {
            int srow = mm * 4 + c2;
            int swz = (((srow >> 3) ^ srow) & 7) << 4;
            char* base = reinterpret_cast<char*>(Wl) + srow * 256;
#pragma unroll
            for (int h = 0; h < 2; ++h)
#pragma unroll
                for (int jg = 0; jg < 2; ++jg)
                    *reinterpret_cast<u32x4*>(
                        base + ((h * 128 + nq * 32 + jg * 16) ^ swz)) = pkp[c2][h][jg];
        }
    }

    // ---- X tile builder (16 cols x 128 k) ----
    auto buildX = [&](int bb, const float4& a4, const float4& p4) {
        float s0, c0, s1, c1, s2, c2, s3, c3;
        sincos_rad(p4.x, s0, c0);
        sincos_rad(p4.y, s1, c1);
        sincos_rad(p4.z, s2, c2);
        sincos_rad(p4.w, s3, c3);
        unsigned int re01 = pk2(a4.x * c0, a4.y * c1);
        unsigned int re23 = pk2(a4.z * c2, a4.w * c3);
        unsigned int im01 = pk2(a4.x * s0, a4.y * s1);
        unsigned int im23 = pk2(a4.z * s2, a4.w * s3);
        int swz = (xc & 7) << 4;
        char* rowp = reinterpret_cast<char*>(Xt[bb]) + xc * 256;
        *reinterpret_cast<uint2*>(rowp + ((xn4 * 8) ^ swz)) = make_uint2(re01, re23);
        *reinterpret_cast<uint2*>(rowp + ((128 + xn4 * 8) ^ swz)) = make_uint2(im01, im23);
    };

    buildX(0, am0, pv0);
    __syncthreads();   // W + X0 visible

    // ---- wf: this wave's 128 Y-rows x 128 k, derived from stored re-rows ----
    s16x8 wf[8][4];
#pragma unroll
    for (int rt = 0; rt < 8; ++rt) {
        int row = wave * 128 + rt * 16 + lrow;    // conceptual Y row
        int srow = (row >> 3) * 4 + ((lrow & 7) >> 1);
        int p = lrow & 1;
        int swz = (((srow >> 3) ^ srow) & 7) << 4;
        const char* base = reinterpret_cast<const char*>(Wl) + srow * 256;
        s16x8 st[4];
#pragma unroll
        for (int kk = 0; kk < 4; ++kk)
            st[kk] = *reinterpret_cast<const s16x8*>(
                base + ((kk * 64 + lkgrp * 16) ^ swz));
        // even row: [s*cre | -s*cim] = st ; odd row: [s*cim | s*cre]
        wf[rt][0] = p ? negbf(st[2]) : st[0];
        wf[rt][1] = p ? negbf(st[3]) : st[1];
        wf[rt][2] = p ? st[0] : st[2];
        wf[rt][3] = p ? st[1] : st[3];
    }

    float lpart = 0.f;

#pragma unroll
    for (int it = 0; it < 4; ++it) {
        // xf from current buffer (B operand: col = lrow)
        s16x8 xf[4];
        {
            int swz = (lrow & 7) << 4;
            const char* rowp = reinterpret_cast<const char*>(Xt[it & 1]) + lrow * 256;
#pragma unroll
            for (int kk = 0; kk < 4; ++kk)
                xf[kk] = *reinterpret_cast<const s16x8*>(
                    rowp + ((kk * 64 + lkgrp * 16) ^ swz));
        }
        // issue depth-2 amp/ph prefetch (tile it+2)
        float4 amN, pvN;
        if (it < 2) {
            int off = baseA + (it + 2) * 16 * 64;
            amN = *reinterpret_cast<const float4*>(amp + off);
            pvN = *reinterpret_cast<const float4*>(ph + off);
        }
        // issue te prefetch (tile it+1)
        if (it < 3) {
            int off = teB + (it + 1) * 16 * 64;
#pragma unroll
            for (int rt = 0; rt < 8; ++rt) teN[rt] = te[off + rt * 2];
        }
        // MFMA: 8 row-tiles x K=128
        f32x4 acc[8];
#pragma unroll
        for (int rt = 0; rt < 8; ++rt) {
            acc[rt] = {0.f, 0.f, 0.f, 0.f};
#pragma unroll
            for (int kk = 0; kk < 4; ++kk)
                acc[rt] = __builtin_amdgcn_mfma_f32_16x16x32_bf16(wf[rt][kk], xf[kk],
                                                                  acc[rt], 0, 0, 0);
        }
        // build next tile (source regs loaded one phase earlier), overlaps MFMA
        if (it < 3) buildX((it + 1) & 1, amCur, pvCur);
        // epilogue: D layout col=lane&15, row=lkgrp*4+reg
#pragma unroll
        for (int rt = 0; rt < 8; ++rt) {
            float q0 = acc[rt].x * acc[rt].x;
            float q1 = acc[rt].y * acc[rt].y;
            float q2 = acc[rt].z * acc[rt].z;
            float q3 = acc[rt].w * acc[rt].w;
            float part = (lkgrp & 1) ? (-(q0 + q1 + q2 + q3)) : (q0 + q1 - q2 - q3);
            float pred = part + __shfl_xor(part, 16);
            float d = pred - teU[rt];
            lpart = fmaf(0.5f * d, d, lpart);   // each (b,m) in 2 lanes
        }
        // rotate pipeline registers
        if (it < 2) { amCur = amN; pvCur = pvN; }
        if (it < 3) {
#pragma unroll
            for (int rt = 0; rt < 8; ++rt) teU[rt] = teN[rt];
            __syncthreads();   // single barrier per iter
        }
    }

    // ---- block reduction (deterministic) + plain store; kernel boundary
    //      provides cross-block visibility for the finalize kernel ----
#pragma unroll
    for (int off = 32; off >= 1; off >>= 1)
        lpart += __shfl_xor(lpart, off);
    if (lane == 0) sred[wave] = (double)lpart;
    __syncthreads();
    if (t == 0)
        partials[blk] = sred[0] + sred[1] + sred[2] + sred[3];
}

// ---- finalize: 1 block, 512 threads (kernel-boundary handoff, R10) ----
__global__ void finalize(const double* __restrict__ partials,
                         float* __restrict__ out) {
    __shared__ double sred[8];
    const int t = threadIdx.x;
    const int wave = t >> 6, lane = t & 63;
    double v = partials[t];
#pragma unroll
    for (int off = 32; off >= 1; off >>= 1)
        v += __shfl_xor(v, off);
    if (lane == 0) sred[wave] = v;
    __syncthreads();
    if (t == 0)
        out[0] = (float)((sred[0] + sred[1] + sred[2] + sred[3] +
                          sred[4] + sred[5] + sred[6] + sred[7]) /
                         (double)(B_TOTAL * 64));
}

extern "C" void kernel_launch(void* const* d_in, const int* in_sizes, int n_in,
                              void* d_out, int out_size, void* d_ws, size_t ws_size,
                              hipStream_t stream) {
    const float* amp = (const float*)d_in[0];
    const float* ph  = (const float*)d_in[1];
    const float* te  = (const float*)d_in[2];

    double* partials = (double*)d_ws;   // 512 * 8 B

    fused_energy<<<512, 256, 0, stream>>>(amp, ph, te, partials);
    finalize<<<1, 512, 0, stream>>>(partials, (float*)d_out);
}

// Round 12
// 18.296 us; speedup vs baseline: 1.0685x; 1.0685x over previous
//
#include <hip/hip_runtime.h>
#include <hip/hip_bf16.h>

// R12 = clean revert to R10 (best validated: 18.3us, absmax 0.0).
// Fused main kernel + tiny finalize kernel.
//   Y[512 x B] = W[512 x 128] * X[128 x B]
//   W rows per m (8): [h_re, h_im, q0_re, q0_im, q1_re, q1_im, q2_re, q2_im]
//     (scaled by s1=sqrt(1e5*C1) for h rows, s2=sqrt(1e5*|C2|) for q rows)
//   X[:,b] = [amp*cos(ph) (64) ; amp*sin(ph) (64)]
//   pred[b,m] = Y[8m]^2 + Y[8m+1]^2 - sum(Y[8m+2..8m+7]^2)
//   loss = mean((pred - true)^2)
// W recomputed on-device (validated R4/R5/R8/R10). Analytic q derivative.
// Trig: hand-rolled Taylor sincos (validated R8/R10; amdgcn trig builtins
// produced wrong results R6/R7).
// Cross-block handoff: KERNEL BOUNDARY (validated R10). In-kernel non-fence
// tails race on gfx950 (R6/R7/R9); fence tail costs ~5us of L2 sweeps (R3).
// R11's 2-blocks/CU split regressed (W-build is per-block fixed cost ->
// anti-amortizes with more blocks): 19.5 vs 18.3. Reverted.

typedef short s16x8 __attribute__((ext_vector_type(8)));
typedef float f32x4 __attribute__((ext_vector_type(4)));
typedef unsigned int u32x4 __attribute__((ext_vector_type(4)));

#define B_TOTAL 32768

constexpr double PI_ = 3.14159265358979323846;
constexpr double RHO_ = 1.225, CS_ = 343.0, FREQ_ = 40000.0, UU_ = 3.086, AREA_ = 0.0008;
constexpr double KW_ = 2.0 * PI_ * FREQ_ / CS_;
constexpr double WW_ = 2.0 * PI_ * FREQ_;
constexpr double RR_ = 0.000865;
constexpr double CONSTV_ = 2.0 * PI_ * RR_ * RR_ * RR_;
constexpr double C1E5_ = CONSTV_ / (6.0 * RHO_ * CS_ * CS_) * 100000.0;
constexpr double C2E5_ = CONSTV_ * RHO_ / 4.0 * 100000.0;   // = -C2 * 1e5
constexpr double GG_ = AREA_ * RHO_ * CS_ * KW_ * UU_ / (2.0 * PI_);

__device__ inline unsigned int pk2(float a, float b) {   // -> v_cvt_pk_bf16_f32
    __hip_bfloat162 h = __float22bfloat162_rn(make_float2(a, b));
    unsigned int u;
    __builtin_memcpy(&u, &h, 4);
    return u;
}

// Branchless Taylor sincos for u in [-pi, pi]. |err| <= ~1e-6. (validated R8)
__device__ inline void poly_sincos(float u, float& s, float& c) {
    float u2 = u * u;
    float sp = fmaf(u2, -7.6471637e-13f, 1.6059044e-10f);
    sp = fmaf(u2, sp, -2.5052108e-8f);
    sp = fmaf(u2, sp, 2.7557319e-6f);
    sp = fmaf(u2, sp, -1.9841270e-4f);
    sp = fmaf(u2, sp, 8.3333335e-3f);
    sp = fmaf(u2, sp, -0.16666667f);
    s = u * fmaf(u2, sp, 1.0f);
    float cp = fmaf(u2, -1.1470746e-11f, 2.0876757e-9f);
    cp = fmaf(u2, cp, -2.7557319e-7f);
    cp = fmaf(u2, cp, 2.4801587e-5f);
    cp = fmaf(u2, cp, -1.3888889e-3f);
    cp = fmaf(u2, cp, 4.1666668e-2f);
    cp = fmaf(u2, cp, -0.5f);
    c = fmaf(u2, cp, 1.0f);
}

// sin/cos(2*pi*t) for t ~ O(16): reduce t to [-0.5,0.5], scale.
__device__ inline void sincos_2pit(float t, float& s, float& c) {
    float x = t - rintf(t);              // [-0.5, 0.5]
    poly_sincos(x * 6.2831853e+0f, s, c);
}

// sin/cos(p) for p in [0, 2*pi): one Cody-Waite step.
__device__ inline void sincos_rad(float p, float& s, float& c) {
    const float INV2PI = 0.15915494309189535f;
    float n = rintf(p * INV2PI);         // 0 or 1
    poly_sincos(fmaf(n, -6.2831853e+0f, p), s, c);
}

__global__ __launch_bounds__(512, 2)
void fused_energy(const float* __restrict__ amp, const float* __restrict__ ph,
                  const float* __restrict__ te,
                  double* __restrict__ partials) {
    __shared__ unsigned short Wl[512 * 128];     // 128 KB, XOR-swizzled 256B rows
    __shared__ unsigned short Xt[2][32 * 128];   // 2 x 8 KB double buffer
    __shared__ double sred[8];

    const int t = threadIdx.x;
    const int wave = t >> 6, lane = t & 63;
    const int lrow = lane & 15, lkgrp = lane >> 4;
    const int wr = wave & 3, wc = wave >> 2;
    const int blk = blockIdx.x;
    const int xc = t >> 4, xn4 = t & 15;         // X-build mapping: col, n-quad

    // ---- prologue loads: tiles 0,1 amp/ph (float4) + tile0 te ----
    const int baseA = (blk * 128 + xc) * 64 + xn4 * 4;
    float4 am0 = *reinterpret_cast<const float4*>(amp + baseA);
    float4 pv0 = *reinterpret_cast<const float4*>(ph + baseA);
    float4 amCur = *reinterpret_cast<const float4*>(amp + baseA + 32 * 64);
    float4 pvCur = *reinterpret_cast<const float4*>(ph + baseA + 32 * 64);
    const int teB = (blk * 128 + wc * 16 + lrow) * 64 + wr * 16 + (lkgrp >> 1);
    float teU[8], teN[8];
#pragma unroll
    for (int rt = 0; rt < 8; ++rt) teU[rt] = te[teB + rt * 2];

    // ---- W build (validated math), poly trig, cvt_pk packing ----
    {
        const float G1 = sqrtf((float)C1E5_) * (float)GG_;
        const float G2 = sqrtf((float)C2E5_) * (float)(GG_ / (WW_ * RHO_));
        const float KWf = (float)KW_;
        const float REVf = (float)(FREQ_ / CS_);   // t = r * F/c ; kr = 2*pi*t
        int mm = t >> 3, nx = t & 7;
        int mx = mm >> 3, my = mm & 7;
        float dx = ((float)mx - 3.5f) * 0.005f - ((float)nx - 3.5f) * 0.01f;
        const float dz = 0.10f;
        u32x4 pkp[16];
#pragma unroll
        for (int j2 = 0; j2 < 4; ++j2) {
            float va[8], vb[8];
#pragma unroll
            for (int jj = 0; jj < 2; ++jj) {
                int j = j2 * 2 + jj;
                float dy = ((float)my - 3.5f) * 0.005f - ((float)j - 3.5f) * 0.01f;
                float r2 = dx * dx + dy * dy + dz * dz;
                float r = sqrtf(r2);
                float invr = 1.0f / r;
                float kr = KWf * r;
                float S, C;
                sincos_2pit(REVf * r, S, C);       // S=sin(kr), C=cos(kr)
                float hb = G1 * invr;
                float qb = G2 * invr * invr * invr;
                float t1 = kr * S + C, t2 = kr * C - S;
                float* v = jj ? vb : va;
                v[0] = hb * S;      v[1] = hb * C;
                v[2] = qb * dx * t1; v[3] = qb * dx * t2;
                v[4] = qb * dy * t1; v[5] = qb * dy * t2;
                v[6] = qb * dz * t1; v[7] = qb * dz * t2;
            }
            const int  rs[16] = {0,1,1,0, 2,3,3,2, 4,5,5,4, 6,7,7,6};
            const bool rn[16] = {false,true,false,false, false,true,false,false,
                                 false,true,false,false, false,true,false,false};
#pragma unroll
            for (int r = 0; r < 16; ++r) {
                float a = va[rs[r]], b = vb[rs[r]];
                pkp[r][j2] = rn[r] ? pk2(-a, -b) : pk2(a, b);
            }
        }
#pragma unroll
        for (int r8 = 0; r8 < 8; ++r8) {
            int row = mm * 8 + r8;
            int swz = (((row >> 3) ^ row) & 7) << 4;
            char* base = reinterpret_cast<char*>(Wl) + row * 256;
            *reinterpret_cast<u32x4*>(base + ((nx * 16) ^ swz)) = pkp[r8 * 2];
            *reinterpret_cast<u32x4*>(base + ((nx * 16 + 128) ^ swz)) = pkp[r8 * 2 + 1];
        }
    }

    // ---- X tile builder (col xc, quad xn4) ----
    auto buildX = [&](int bb, const float4& a4, const float4& p4) {
        float s0, c0, s1, c1, s2, c2, s3, c3;
        sincos_rad(p4.x, s0, c0);
        sincos_rad(p4.y, s1, c1);
        sincos_rad(p4.z, s2, c2);
        sincos_rad(p4.w, s3, c3);
        unsigned int re01 = pk2(a4.x * c0, a4.y * c1);
        unsigned int re23 = pk2(a4.z * c2, a4.w * c3);
        unsigned int im01 = pk2(a4.x * s0, a4.y * s1);
        unsigned int im23 = pk2(a4.z * s2, a4.w * s3);
        int swz = (xc & 7) << 4;
        char* rowp = reinterpret_cast<char*>(Xt[bb]) + xc * 256;
        *reinterpret_cast<uint2*>(rowp + ((xn4 * 8) ^ swz)) = make_uint2(re01, re23);
        *reinterpret_cast<uint2*>(rowp + ((128 + xn4 * 8) ^ swz)) = make_uint2(im01, im23);
    };

    buildX(0, am0, pv0);
    __syncthreads();   // W + X0 visible

    // ---- wf: this wave's 128x128 W slice into registers ----
    s16x8 wf[8][4];
#pragma unroll
    for (int rt = 0; rt < 8; ++rt) {
        int row = wr * 128 + rt * 16 + lrow;
        int swz = (((row >> 3) ^ row) & 7) << 4;
        const char* base = reinterpret_cast<const char*>(Wl) + row * 256;
#pragma unroll
        for (int kk = 0; kk < 4; ++kk)
            wf[rt][kk] = *reinterpret_cast<const s16x8*>(base + ((kk * 64 + lkgrp * 16) ^ swz));
    }

    float lpart = 0.f;

#pragma unroll
    for (int it = 0; it < 4; ++it) {
        // xf from current buffer
        s16x8 xf[4];
        {
            int c = wc * 16 + lrow;
            int swz = (c & 7) << 4;
            const char* rowp = reinterpret_cast<const char*>(Xt[it & 1]) + c * 256;
#pragma unroll
            for (int kk = 0; kk < 4; ++kk)
                xf[kk] = *reinterpret_cast<const s16x8*>(rowp + ((kk * 64 + lkgrp * 16) ^ swz));
        }
        // issue depth-2 amp/ph prefetch (tile it+2)
        float4 amN, pvN;
        if (it < 2) {
            int off = baseA + (it + 2) * 32 * 64;
            amN = *reinterpret_cast<const float4*>(amp + off);
            pvN = *reinterpret_cast<const float4*>(ph + off);
        }
        // issue te prefetch (tile it+1)
        if (it < 3) {
            int off = teB + (it + 1) * 32 * 64;
#pragma unroll
            for (int rt = 0; rt < 8; ++rt) teN[rt] = te[off + rt * 2];
        }
        // MFMA: 8 row-tiles x K=128
        f32x4 acc[8];
#pragma unroll
        for (int rt = 0; rt < 8; ++rt) {
            acc[rt] = {0.f, 0.f, 0.f, 0.f};
#pragma unroll
            for (int kk = 0; kk < 4; ++kk)
                acc[rt] = __builtin_amdgcn_mfma_f32_16x16x32_bf16(wf[rt][kk], xf[kk],
                                                                  acc[rt], 0, 0, 0);
        }
        // build next tile (source regs issued one phase earlier), overlaps MFMA
        if (it < 3) buildX((it + 1) & 1, amCur, pvCur);
        // epilogue: D layout col=lane&15, row=lkgrp*4+reg
#pragma unroll
        for (int rt = 0; rt < 8; ++rt) {
            float q0 = acc[rt].x * acc[rt].x;
            float q1 = acc[rt].y * acc[rt].y;
            float q2 = acc[rt].z * acc[rt].z;
            float q3 = acc[rt].w * acc[rt].w;
            float part = (lkgrp & 1) ? (-(q0 + q1 + q2 + q3)) : (q0 + q1 - q2 - q3);
            float pred = part + __shfl_xor(part, 16);
            float d = pred - teU[rt];
            lpart = fmaf(0.5f * d, d, lpart);   // each (b,m) in 2 lanes
        }
        // rotate pipeline registers
        if (it < 2) { amCur = amN; pvCur = pvN; }
        if (it < 3) {
#pragma unroll
            for (int rt = 0; rt < 8; ++rt) teU[rt] = teN[rt];
            __syncthreads();   // single barrier per iter
        }
    }

    // ---- block reduction (deterministic) + plain store; kernel boundary
    //      provides cross-block visibility for the finalize kernel ----
#pragma unroll
    for (int off = 32; off >= 1; off >>= 1)
        lpart += __shfl_xor(lpart, off);
    if (lane == 0) sred[wave] = (double)lpart;
    __syncthreads();
    if (t == 0)
        partials[blk] = sred[0] + sred[1] + sred[2] + sred[3] +
                        sred[4] + sred[5] + sred[6] + sred[7];
}

// ---- finalize: 1 block, 256 threads (validated pattern, R10) ----
__global__ void finalize(const double* __restrict__ partials,
                         float* __restrict__ out) {
    __shared__ double sred[4];
    const int t = threadIdx.x;
    const int wave = t >> 6, lane = t & 63;
    double v = partials[t];
#pragma unroll
    for (int off = 32; off >= 1; off >>= 1)
        v += __shfl_xor(v, off);
    if (lane == 0) sred[wave] = v;
    __syncthreads();
    if (t == 0)
        out[0] = (float)((sred[0] + sred[1] + sred[2] + sred[3]) /
                         (double)(B_TOTAL * 64));
}

extern "C" void kernel_launch(void* const* d_in, const int* in_sizes, int n_in,
                              void* d_out, int out_size, void* d_ws, size_t ws_size,
                              hipStream_t stream) {
    const float* amp = (const float*)d_in[0];
    const float* ph  = (const float*)d_in[1];
    const float* te  = (const float*)d_in[2];

    double* partials = (double*)d_ws;   // 256 * 8 B

    fused_energy<<<256, 512, 0, stream>>>(amp, ph, te, partials);
    finalize<<<1, 256, 0, stream>>>(partials, (float*)d_out);
}